// Round 11
// baseline (965.334 us; speedup 1.0000x reference)
//
#include <hip/hip_runtime.h>
#include <hip/hip_bf16.h>

#define NQ 8
#define NC 1024
#define DD 128
#define BB 16
#define SS 2048
#define RR (BB * SS)   // 32768 rows
#define GAMMA_F 0.99f
#define TAU 0.03f

typedef __attribute__((ext_vector_type(8))) short bf16x8;
typedef __attribute__((ext_vector_type(4))) float f32x4;

__device__ __forceinline__ ushort f2bf(float x) {
  __hip_bfloat16 b = __float2bfloat16(x);
  return *reinterpret_cast<ushort*>(&b);
}
__device__ __forceinline__ float bf2f(ushort u) {
  unsigned v = ((unsigned)u) << 16;
  return *reinterpret_cast<float*>(&v);
}

// ---------------------------------------------------------------- transpose in
__global__ __launch_bounds__(256) void k_transpose_in(
    const float* __restrict__ data, float* __restrict__ res)
{
  __shared__ float tile[32][33];
  int b = blockIdx.z;
  int s0 = blockIdx.x << 5, d0 = blockIdx.y << 5;
  int tx = threadIdx.x, ty = threadIdx.y;   // (32,8)
  #pragma unroll
  for (int r = 0; r < 32; r += 8)
    tile[ty + r][tx] = data[((size_t)b * DD + d0 + ty + r) * SS + s0 + tx];
  __syncthreads();
  #pragma unroll
  for (int r = 0; r < 32; r += 8)
    res[((size_t)b * SS + s0 + ty + r) * DD + d0 + tx] = tile[tx][ty + r];
}

// ---------------------------------------------------------------- ||W||^2
__global__ void k_wsq(const float* __restrict__ W, float* __restrict__ wsq)
{
  int c = blockIdx.x * blockDim.x + threadIdx.x;
  if (c >= NQ * NC) return;
  const float4* p = reinterpret_cast<const float4*>(W + (size_t)c * DD);
  float s = 0.f;
  #pragma unroll 8
  for (int k = 0; k < DD / 4; ++k) {
    float4 v = p[k];
    s += v.x * v.x + v.y * v.y + v.z * v.z + v.w * v.w;
  }
  wsq[c] = s;
}

// ---------------------------------------------------------------- bf16 hi/lo split (tiled layout)
// granule(row, ks, h, kg) = ((row>>4)*8 + ks*2 + h)*64 + kg*16 + (row&15); 8 ushorts each.
// Each (tile, ks, h) is a contiguous 1 KB block where lane l holds granule l.
__global__ __launch_bounds__(256) void k_split(
    const float* __restrict__ src, ushort* __restrict__ dst)
{
  int i = blockIdx.x * 256 + threadIdx.x;
  int row = i >> 2, ks = i & 3;
  const float4* sp = reinterpret_cast<const float4*>(src + (size_t)row * DD + ks * 32);
  size_t gb = ((size_t)(row >> 4) * 8 + ks * 2) * 64 + (row & 15);
  #pragma unroll
  for (int kg = 0; kg < 4; ++kg) {
    float4 a = sp[kg * 2], b = sp[kg * 2 + 1];
    ushort4 h0, h1, l0, l1;
    h0.x = f2bf(a.x); l0.x = f2bf(a.x - bf2f(h0.x));
    h0.y = f2bf(a.y); l0.y = f2bf(a.y - bf2f(h0.y));
    h0.z = f2bf(a.z); l0.z = f2bf(a.z - bf2f(h0.z));
    h0.w = f2bf(a.w); l0.w = f2bf(a.w - bf2f(h0.w));
    h1.x = f2bf(b.x); l1.x = f2bf(b.x - bf2f(h1.x));
    h1.y = f2bf(b.y); l1.y = f2bf(b.y - bf2f(h1.y));
    h1.z = f2bf(b.z); l1.z = f2bf(b.z - bf2f(h1.z));
    h1.w = f2bf(b.w); l1.w = f2bf(b.w - bf2f(h1.w));
    ushort* ph = dst + (gb + kg * 16) * 8;          // h=0
    *reinterpret_cast<ushort4*>(ph) = h0;
    *reinterpret_cast<ushort4*>(ph + 4) = h1;
    ushort* pl = ph + 64 * 8;                        // h=1 (+64 granules)
    *reinterpret_cast<ushort4*>(pl) = l0;
    *reinterpret_cast<ushort4*>(pl + 4) = l1;
  }
}

// ---------------------------------------------------------------- MFMA argmin (LDS-free, barrier-free)
// 256 thr = 4 independent waves; wave w owns rows row0 + w*16 .. +15.
// 64 ct-tiles of 16 codes; B frags global->reg (coalesced 1KB loads, L1/L2-hot).
// 3-term exact split hh + lh + hl in two MFMA chains.
__global__ __launch_bounds__(256, 3) void k_argmin(
    const ushort* __restrict__ res_hl, const ushort* __restrict__ w_hl,
    const float* __restrict__ wsq,
    int* __restrict__ idxw, float* __restrict__ idxf,
    int* __restrict__ count, int* __restrict__ fb_count,
    int* __restrict__ fb_list, int stage)
{
  const int t = threadIdx.x;
  const int l = t & 63;
  const int w = t >> 6;            // 0..3
  const int l15 = l & 15;
  const int row0 = blockIdx.x * 64;
  const float* wsqs = wsq + stage * NC;
  const ushort* wb = w_hl + (size_t)stage * NC * 256;

  // A fragments: tile = row0/16 + w; lane l reads granule l of each (ks,h) block.
  const size_t ab = ((size_t)(row0 >> 4) + w) * 8;
  bf16x8 ah[4], al[4];
  #pragma unroll
  for (int ks = 0; ks < 4; ++ks) {
    ah[ks] = *reinterpret_cast<const bf16x8*>(res_hl + ((ab + ks * 2) * 64 + l) * 8);
    al[ks] = *reinterpret_cast<const bf16x8*>(res_hl + ((ab + ks * 2 + 1) * 64 + l) * 8);
  }

  float m1[4], m2[4];
  int i1[4];
  #pragma unroll
  for (int rg = 0; rg < 4; ++rg) { m1[rg] = 3.4e38f; m2[rg] = 3.4e38f; i1[rg] = 0; }

  bf16x8 bh0[4], bl0[4], bh1[4], bl1[4];

#define LOADB(BH, BL, CT) {                                                       \
    size_t bb = (size_t)(CT) * 8;                                                 \
    _Pragma("unroll")                                                             \
    for (int ks = 0; ks < 4; ++ks) {                                              \
      BH[ks] = *reinterpret_cast<const bf16x8*>(wb + ((bb + ks * 2) * 64 + l) * 8);        \
      BL[ks] = *reinterpret_cast<const bf16x8*>(wb + ((bb + ks * 2 + 1) * 64 + l) * 8);    \
    } }

#define COMPUTE(BH, BL, CT) {                                                     \
    f32x4 accP = {0.f, 0.f, 0.f, 0.f};                                            \
    f32x4 accQ = {0.f, 0.f, 0.f, 0.f};                                            \
    _Pragma("unroll")                                                             \
    for (int ks = 0; ks < 4; ++ks) {                                              \
      accP = __builtin_amdgcn_mfma_f32_16x16x32_bf16(ah[ks], BH[ks], accP, 0, 0, 0); \
      accQ = __builtin_amdgcn_mfma_f32_16x16x32_bf16(al[ks], BH[ks], accQ, 0, 0, 0); \
      accQ = __builtin_amdgcn_mfma_f32_16x16x32_bf16(ah[ks], BL[ks], accQ, 0, 0, 0); \
    }                                                                             \
    int code = (CT) * 16 + l15;                                                   \
    float sq = wsqs[code];                                                        \
    _Pragma("unroll")                                                             \
    for (int rg = 0; rg < 4; ++rg) {                                              \
      float s = fmaf(-2.f, accP[rg] + accQ[rg], sq);                              \
      if (s < m1[rg]) { m2[rg] = m1[rg]; m1[rg] = s; i1[rg] = code; }             \
      else if (s < m2[rg]) m2[rg] = s;                                            \
    } }

  LOADB(bh0, bl0, 0);
  for (int ct = 0; ct < 64; ct += 2) {
    LOADB(bh1, bl1, ct + 1);
    COMPUTE(bh0, bl0, ct);
    if (ct + 2 < 64) LOADB(bh0, bl0, ct + 2);
    COMPUTE(bh1, bl1, ct + 1);
  }
#undef LOADB
#undef COMPUTE

  // butterfly over the 16 code-classes (lane bits 0..3; kg group preserved)
  #pragma unroll
  for (int mk = 1; mk <= 8; mk <<= 1) {
    #pragma unroll
    for (int rg = 0; rg < 4; ++rg) {
      float om1 = __shfl_xor(m1[rg], mk);
      int   oi  = __shfl_xor(i1[rg], mk);
      float om2 = __shfl_xor(m2[rg], mk);
      bool bwin = (om1 < m1[rg]) || (om1 == m1[rg] && oi < i1[rg]);
      float lose = bwin ? m1[rg] : om1;
      m2[rg] = fminf(fminf(m2[rg], om2), lose);
      if (bwin) { m1[rg] = om1; i1[rg] = oi; }
    }
  }
  if (l15 == 0) {
    int kg = l >> 4;
    #pragma unroll
    for (int rg = 0; rg < 4; ++rg) {
      int row = row0 + w * 16 + kg * 4 + rg;
      if (m2[rg] - m1[rg] > TAU) {
        idxw[row] = i1[rg];
        idxf[row] = (float)i1[rg];
        atomicAdd(&count[i1[rg]], 1);
      } else {
        int p = atomicAdd(fb_count, 1);
        fb_list[p] = row;
      }
    }
  }
}

// ---------------------------------------------------------------- exact fp32 fallback
__global__ __launch_bounds__(256) void k_fallback(
    const float* __restrict__ res, const float* __restrict__ W,
    const float* __restrict__ wsq, const int* __restrict__ fb_count,
    const int* __restrict__ fb_list,
    int* __restrict__ idxw, float* __restrict__ idxf,
    int* __restrict__ count, int stage)
{
  __shared__ float rr[128];
  __shared__ float sv[256];
  __shared__ int   si[256];
  int n = *fb_count;
  int t = threadIdx.x;
  for (int b = blockIdx.x; b < n; b += gridDim.x) {
    int row = fb_list[b];
    __syncthreads();
    if (t < 128) rr[t] = res[(size_t)row * DD + t];
    __syncthreads();
    float bm = 3.4e38f; int bi = 0;
    #pragma unroll
    for (int j = 0; j < 4; ++j) {
      int c = t + j * 256;
      const float4* wp = reinterpret_cast<const float4*>(W + ((size_t)stage * NC + c) * DD);
      float dot = 0.f;
      #pragma unroll 8
      for (int k = 0; k < 32; ++k) {
        float4 wv = wp[k];
        dot = fmaf(rr[4 * k + 0], wv.x, dot);
        dot = fmaf(rr[4 * k + 1], wv.y, dot);
        dot = fmaf(rr[4 * k + 2], wv.z, dot);
        dot = fmaf(rr[4 * k + 3], wv.w, dot);
      }
      float s = fmaf(-2.f, dot, wsq[stage * NC + c]);
      if (s < bm || (s == bm && c < bi)) { bm = s; bi = c; }
    }
    sv[t] = bm; si[t] = bi;
    __syncthreads();
    for (int sft = 128; sft > 0; sft >>= 1) {
      if (t < sft) {
        float ov = sv[t + sft]; int oi = si[t + sft];
        if (ov < sv[t] || (ov == sv[t] && oi < si[t])) { sv[t] = ov; si[t] = oi; }
      }
      __syncthreads();
    }
    if (t == 0) {
      int win = si[0];
      idxw[row] = win;
      idxf[row] = (float)win;
      atomicAdd(&count[win], 1);
    }
  }
}

// ---------------------------------------------------------------- prefix scan + reset for next stage
__global__ __launch_bounds__(1024) void k_scan(
    int* __restrict__ count, int* __restrict__ offs, int* __restrict__ pos)
{
  __shared__ int sc[1024];
  int t = threadIdx.x;
  sc[t] = count[t];
  __syncthreads();
  for (int off = 1; off < 1024; off <<= 1) {
    int v = (t >= off) ? sc[t - off] : 0;
    __syncthreads();
    sc[t] += v;
    __syncthreads();
  }
  offs[t + 1] = sc[t];
  if (t == 0) { offs[0] = 0; count[1024] = 0; }   // count[1024] == fb_count
  pos[t] = 0;
  count[t] = 0;   // ready for next stage's argmin
}

// ---------------------------------------------------------------- CSR scatter
__global__ __launch_bounds__(256) void k_scatter(
    const int* __restrict__ idxw, const int* __restrict__ offs,
    int* __restrict__ pos, int* __restrict__ rows_sorted)
{
  int r = blockIdx.x * 256 + threadIdx.x;
  int c = idxw[r];
  int slot = offs[c] + atomicAdd(&pos[c], 1);
  rows_sorted[slot] = r;
}

// ---------------------------------------------------------------- threefry2x32 (JAX-exact)
__device__ __forceinline__ unsigned rotl32(unsigned v, int r) { return (v << r) | (v >> (32 - r)); }

__device__ void threefry2x32(unsigned ks0, unsigned ks1, unsigned x0, unsigned x1,
                             unsigned& o0, unsigned& o1)
{
  unsigned ks2 = ks0 ^ ks1 ^ 0x1BD11BDAu;
  x0 += ks0; x1 += ks1;
  x0 += x1; x1 = rotl32(x1, 13); x1 ^= x0;
  x0 += x1; x1 = rotl32(x1, 15); x1 ^= x0;
  x0 += x1; x1 = rotl32(x1, 26); x1 ^= x0;
  x0 += x1; x1 = rotl32(x1, 6);  x1 ^= x0;
  x0 += ks1; x1 += ks2 + 1u;
  x0 += x1; x1 = rotl32(x1, 17); x1 ^= x0;
  x0 += x1; x1 = rotl32(x1, 29); x1 ^= x0;
  x0 += x1; x1 = rotl32(x1, 16); x1 ^= x0;
  x0 += x1; x1 = rotl32(x1, 24); x1 ^= x0;
  x0 += ks2; x1 += ks0 + 2u;
  x0 += x1; x1 = rotl32(x1, 13); x1 ^= x0;
  x0 += x1; x1 = rotl32(x1, 15); x1 ^= x0;
  x0 += x1; x1 = rotl32(x1, 26); x1 ^= x0;
  x0 += x1; x1 = rotl32(x1, 6);  x1 ^= x0;
  x0 += ks0; x1 += ks1 + 3u;
  x0 += x1; x1 = rotl32(x1, 17); x1 ^= x0;
  x0 += x1; x1 = rotl32(x1, 29); x1 ^= x0;
  x0 += x1; x1 = rotl32(x1, 16); x1 ^= x0;
  x0 += x1; x1 = rotl32(x1, 24); x1 ^= x0;
  x0 += ks1; x1 += ks2 + 4u;
  x0 += x1; x1 = rotl32(x1, 13); x1 ^= x0;
  x0 += x1; x1 = rotl32(x1, 15); x1 ^= x0;
  x0 += x1; x1 = rotl32(x1, 26); x1 ^= x0;
  x0 += x1; x1 = rotl32(x1, 6);  x1 ^= x0;
  x0 += ks2; x1 += ks0 + 5u;
  o0 = x0; o1 = x1;
}

// ---------------------------------------------------------------- EMA / dead codes
__global__ __launch_bounds__(1024) void k_finalize(
    const float* __restrict__ Ni_in, const float* __restrict__ mi_in,
    const int* __restrict__ offs, const int* __restrict__ rows_sorted,
    const float* __restrict__ res_cur,
    float* __restrict__ outNi, float* __restrict__ outmi, float* __restrict__ outW,
    int stage)
{
  __shared__ float red[8][128];
  const float ONEMG = (float)(1.0 - 0.99);
  int c = blockIdx.x;
  int t = threadIdx.x;
  int d = t & 127;
  int jw = t >> 7;             // 0..7
  int base = offs[c];
  int cnt = offs[c + 1] - base;
  const int* rs = rows_sorted + base;

  float sum = 0.f;
  int j = jw;
  for (; j + 24 < cnt; j += 32) {
    int r0 = rs[j];
    int r1 = rs[j + 8];
    int r2 = rs[j + 16];
    int r3 = rs[j + 24];
    float v0 = res_cur[(size_t)r0 * DD + d];
    float v1 = res_cur[(size_t)r1 * DD + d];
    float v2 = res_cur[(size_t)r2 * DD + d];
    float v3 = res_cur[(size_t)r3 * DD + d];
    sum += v0 + v1 + v2 + v3;
  }
  for (; j < cnt; j += 8)
    sum += res_cur[(size_t)rs[j] * DD + d];

  red[jw][d] = sum;
  __syncthreads();

  if (jw == 0) {
    float s = red[0][d] + red[1][d] + red[2][d] + red[3][d]
            + red[4][d] + red[5][d] + red[6][d] + red[7][d];
    float ni = Ni_in[stage * NC + c] * GAMMA_F + (float)cnt * ONEMG;
    float mm = mi_in[((size_t)stage * NC + c) * DD + d] * GAMMA_F + s * ONEMG;
    float w = mm / fmaxf(ni, 1e-8f);
    if (ni < 2.0f) {
      unsigned K0, K1, a0, a1, b0, b1, o0, o1;
      threefry2x32(0u, 42u, 0u, (unsigned)stage, K0, K1);
      threefry2x32(K0, K1, 0u, 2u, a0, a1);
      threefry2x32(K0, K1, 1u, 3u, b0, b1);
      unsigned bits;
      if (c < 512) { threefry2x32(a1, b1, (unsigned)c, (unsigned)(c + 512), o0, o1); bits = o0; }
      else         { threefry2x32(a1, b1, (unsigned)(c - 512), (unsigned)c, o0, o1); bits = o1; }
      int rid = (int)(bits & 32767u);
      w = res_cur[(size_t)rid * DD + d];
    }
    if (d == 0) outNi[stage * NC + c] = ni;
    size_t o = ((size_t)stage * NC + c) * DD + d;
    outmi[o] = mm;
    outW[o] = w;
  }
}

// ---------------------------------------------------------------- residual update (in-place) + tiled bf16 split
__global__ __launch_bounds__(256) void k_update(
    float* __restrict__ res, const float* __restrict__ W,
    const int* __restrict__ idx, ushort* __restrict__ res_hl, int stage)
{
  int row = blockIdx.x * 16 + (threadIdx.x >> 4);
  int g = threadIdx.x & 15;          // dims [g*8, g*8+8)
  int id = idx[row];
  const float4* rp = reinterpret_cast<const float4*>(res + (size_t)row * DD + g * 8);
  const float4* qp = reinterpret_cast<const float4*>(W + ((size_t)stage * NC + id) * DD + g * 8);
  float4 r0 = rp[0], r1 = rp[1];
  float4 q0 = qp[0], q1 = qp[1];
  float4 o0, o1;
  o0.x = r0.x - q0.x; o0.y = r0.y - q0.y; o0.z = r0.z - q0.z; o0.w = r0.w - q0.w;
  o1.x = r1.x - q1.x; o1.y = r1.y - q1.y; o1.z = r1.z - q1.z; o1.w = r1.w - q1.w;
  float4* wp2 = reinterpret_cast<float4*>(res + (size_t)row * DD + g * 8);
  wp2[0] = o0; wp2[1] = o1;
  ushort4 h0, h1, l0, l1;
  h0.x = f2bf(o0.x); l0.x = f2bf(o0.x - bf2f(h0.x));
  h0.y = f2bf(o0.y); l0.y = f2bf(o0.y - bf2f(h0.y));
  h0.z = f2bf(o0.z); l0.z = f2bf(o0.z - bf2f(h0.z));
  h0.w = f2bf(o0.w); l0.w = f2bf(o0.w - bf2f(h0.w));
  h1.x = f2bf(o1.x); l1.x = f2bf(o1.x - bf2f(h1.x));
  h1.y = f2bf(o1.y); l1.y = f2bf(o1.y - bf2f(h1.y));
  h1.z = f2bf(o1.z); l1.z = f2bf(o1.z - bf2f(h1.z));
  h1.w = f2bf(o1.w); l1.w = f2bf(o1.w - bf2f(h1.w));
  int ks = g >> 2, kg = g & 3;
  size_t gb = ((size_t)(row >> 4) * 8 + ks * 2) * 64 + kg * 16 + (row & 15);
  ushort* ph = res_hl + gb * 8;
  *reinterpret_cast<ushort4*>(ph) = h0;
  *reinterpret_cast<ushort4*>(ph + 4) = h1;
  ushort* pl = ph + 64 * 8;
  *reinterpret_cast<ushort4*>(pl) = l0;
  *reinterpret_cast<ushort4*>(pl + 4) = l1;
}

// ---------------------------------------------------------------- logits + loss partials
__global__ __launch_bounds__(256) void k_final(
    const float* __restrict__ data, const float* __restrict__ res,
    float* __restrict__ logits, float* __restrict__ partials)
{
  __shared__ float tile[32][33];
  __shared__ float wsum[4];
  int b = blockIdx.z, s0 = blockIdx.x << 5, d0 = blockIdx.y << 5;
  int tx = threadIdx.x, ty = threadIdx.y;
  #pragma unroll
  for (int r = 0; r < 32; r += 8)
    tile[ty + r][tx] = res[((size_t)b * SS + s0 + ty + r) * DD + d0 + tx];
  __syncthreads();
  float l = 0.f;
  #pragma unroll
  for (int r = 0; r < 32; r += 8) {
    int dv = d0 + ty + r, s = s0 + tx;
    size_t o = ((size_t)b * DD + dv) * SS + s;
    float rv = tile[tx][ty + r];
    logits[o] = data[o] - rv;
    l = fmaf(rv, rv, l);
  }
  #pragma unroll
  for (int m = 1; m < 64; m <<= 1) l += __shfl_xor(l, m);
  int lin = ty * 32 + tx;
  if ((lin & 63) == 0) wsum[lin >> 6] = l;
  __syncthreads();
  if (lin == 0) {
    int bl = (blockIdx.z * gridDim.y + blockIdx.y) * gridDim.x + blockIdx.x;
    partials[bl] = wsum[0] + wsum[1] + wsum[2] + wsum[3];
  }
}

__global__ __launch_bounds__(1024) void k_loss_reduce(
    const float* __restrict__ partials, float* __restrict__ loss)
{
  __shared__ float ws[16];
  int t = threadIdx.x;
  float s = partials[t] + partials[t + 1024] + partials[t + 2048] + partials[t + 3072];
  #pragma unroll
  for (int m = 1; m < 64; m <<= 1) s += __shfl_xor(s, m);
  if ((t & 63) == 0) ws[t >> 6] = s;
  __syncthreads();
  if (t < 16) {
    float v = ws[t];
    #pragma unroll
    for (int m = 1; m < 16; m <<= 1) v += __shfl_xor(v, m);
    if (t == 0) loss[0] = v * (1.0f / 4194304.0f);
  }
}

// ---------------------------------------------------------------- launch
extern "C" void kernel_launch(void* const* d_in, const int* in_sizes, int n_in,
                              void* d_out, int out_size, void* d_ws, size_t ws_size,
                              hipStream_t stream)
{
  (void)in_sizes; (void)n_in; (void)out_size; (void)ws_size;
  const float* data = (const float*)d_in[0];
  const float* W    = (const float*)d_in[1];
  const float* Ni   = (const float*)d_in[2];
  const float* mi   = (const float*)d_in[3];

  float* out        = (float*)d_out;
  float* out_logits = out;
  float* out_loss   = out + (size_t)BB * DD * SS;
  float* out_idx    = out_loss + 1;
  float* out_Ni     = out_idx + (size_t)NQ * RR;
  float* out_mi     = out_Ni + (size_t)NQ * NC;
  float* out_W      = out_mi + (size_t)NQ * NC * DD;

  char* wp = (char*)d_ws;
  float*  resA        = (float*)wp;   wp += (size_t)RR * DD * 4;       // 16.78 MB
  ushort* res_hl      = (ushort*)wp;  wp += (size_t)RR * DD * 4;       // 16.78 MB
  ushort* w_hl        = (ushort*)wp;  wp += (size_t)NQ * NC * DD * 4;  // 4.19 MB
  float*  wsq         = (float*)wp;   wp += (size_t)NQ * NC * 4;
  int*    idxw        = (int*)wp;     wp += (size_t)RR * 4;
  int*    fb_list     = (int*)wp;     wp += (size_t)RR * 4;
  int*    rows_sorted = (int*)wp;     wp += (size_t)RR * 4;
  int*    count       = (int*)wp;     wp += (size_t)1025 * 4;          // count[1024] + fb_count
  int*    fb_count    = count + 1024;
  int*    pos         = (int*)wp;     wp += (size_t)NC * 4;
  int*    offs        = (int*)wp;     wp += (size_t)(NC + 1) * 4;
  float*  partials    = (float*)wp;   wp += (size_t)4096 * 4;

  k_transpose_in<<<dim3(SS / 32, DD / 32, BB), dim3(32, 8), 0, stream>>>(data, resA);
  k_split<<<RR * 4 / 256, 256, 0, stream>>>(resA, res_hl);
  k_wsq<<<(NQ * NC + 255) / 256, 256, 0, stream>>>(W, wsq);
  k_split<<<NQ * NC * 4 / 256, 256, 0, stream>>>(W, w_hl);
  hipMemsetAsync(count, 0, 1025 * sizeof(int), stream);   // first stage only; k_scan resets after

  for (int i = 0; i < NQ; ++i) {
    k_argmin<<<RR / 64, 256, 0, stream>>>(res_hl, w_hl, wsq, idxw,
                                          out_idx + (size_t)i * RR,
                                          count, fb_count, fb_list, i);
    k_fallback<<<512, 256, 0, stream>>>(resA, W, wsq, fb_count, fb_list,
                                        idxw, out_idx + (size_t)i * RR, count, i);
    k_scan<<<1, 1024, 0, stream>>>(count, offs, pos);
    k_scatter<<<RR / 256, 256, 0, stream>>>(idxw, offs, pos, rows_sorted);
    k_finalize<<<NC, 1024, 0, stream>>>(Ni, mi, offs, rows_sorted, resA,
                                        out_Ni, out_mi, out_W, i);
    k_update<<<RR / 16, 256, 0, stream>>>(resA, W, idxw, res_hl, i);
  }

  k_final<<<dim3(SS / 32, DD / 32, BB), dim3(32, 8), 0, stream>>>(data, resA, out_logits, partials);
  k_loss_reduce<<<1, 1024, 0, stream>>>(partials, out_loss);
}

// Round 12
// 836.936 us; speedup vs baseline: 1.1534x; 1.1534x over previous
//
#include <hip/hip_runtime.h>
#include <hip/hip_bf16.h>

#define NQ 8
#define NC 1024
#define DD 128
#define BB 16
#define SS 2048
#define RR (BB * SS)   // 32768 rows
#define GAMMA_F 0.99f
#define TAU 0.03f

typedef __attribute__((ext_vector_type(8))) short bf16x8;
typedef __attribute__((ext_vector_type(4))) float f32x4;

__device__ __forceinline__ ushort f2bf(float x) {
  __hip_bfloat16 b = __float2bfloat16(x);
  return *reinterpret_cast<ushort*>(&b);
}
__device__ __forceinline__ float bf2f(ushort u) {
  unsigned v = ((unsigned)u) << 16;
  return *reinterpret_cast<float*>(&v);
}

// ---------------------------------------------------------------- transpose in
__global__ __launch_bounds__(256) void k_transpose_in(
    const float* __restrict__ data, float* __restrict__ res)
{
  __shared__ float tile[32][33];
  int b = blockIdx.z;
  int s0 = blockIdx.x << 5, d0 = blockIdx.y << 5;
  int tx = threadIdx.x, ty = threadIdx.y;   // (32,8)
  #pragma unroll
  for (int r = 0; r < 32; r += 8)
    tile[ty + r][tx] = data[((size_t)b * DD + d0 + ty + r) * SS + s0 + tx];
  __syncthreads();
  #pragma unroll
  for (int r = 0; r < 32; r += 8)
    res[((size_t)b * SS + s0 + ty + r) * DD + d0 + tx] = tile[tx][ty + r];
}

// ---------------------------------------------------------------- ||W||^2
__global__ void k_wsq(const float* __restrict__ W, float* __restrict__ wsq)
{
  int c = blockIdx.x * blockDim.x + threadIdx.x;
  if (c >= NQ * NC) return;
  const float4* p = reinterpret_cast<const float4*>(W + (size_t)c * DD);
  float s = 0.f;
  #pragma unroll 8
  for (int k = 0; k < DD / 4; ++k) {
    float4 v = p[k];
    s += v.x * v.x + v.y * v.y + v.z * v.z + v.w * v.w;
  }
  wsq[c] = s;
}

// ---------------------------------------------------------------- bf16 hi/lo split (tiled layout)
// granule(row, ks, h, kg) = ((row>>4)*8 + ks*2 + h)*64 + kg*16 + (row&15); 8 ushorts each.
__global__ __launch_bounds__(256) void k_split(
    const float* __restrict__ src, ushort* __restrict__ dst)
{
  int i = blockIdx.x * 256 + threadIdx.x;
  int row = i >> 2, ks = i & 3;
  const float4* sp = reinterpret_cast<const float4*>(src + (size_t)row * DD + ks * 32);
  size_t gb = ((size_t)(row >> 4) * 8 + ks * 2) * 64 + (row & 15);
  #pragma unroll
  for (int kg = 0; kg < 4; ++kg) {
    float4 a = sp[kg * 2], b = sp[kg * 2 + 1];
    ushort4 h0, h1, l0, l1;
    h0.x = f2bf(a.x); l0.x = f2bf(a.x - bf2f(h0.x));
    h0.y = f2bf(a.y); l0.y = f2bf(a.y - bf2f(h0.y));
    h0.z = f2bf(a.z); l0.z = f2bf(a.z - bf2f(h0.z));
    h0.w = f2bf(a.w); l0.w = f2bf(a.w - bf2f(h0.w));
    h1.x = f2bf(b.x); l1.x = f2bf(b.x - bf2f(h1.x));
    h1.y = f2bf(b.y); l1.y = f2bf(b.y - bf2f(h1.y));
    h1.z = f2bf(b.z); l1.z = f2bf(b.z - bf2f(h1.z));
    h1.w = f2bf(b.w); l1.w = f2bf(b.w - bf2f(h1.w));
    ushort* ph = dst + (gb + kg * 16) * 8;          // h=0
    *reinterpret_cast<ushort4*>(ph) = h0;
    *reinterpret_cast<ushort4*>(ph + 4) = h1;
    ushort* pl = ph + 64 * 8;                        // h=1
    *reinterpret_cast<ushort4*>(pl) = l0;
    *reinterpret_cast<ushort4*>(pl + 4) = l1;
  }
}

// ---------------------------------------------------------------- MFMA argmin + fused update
// 16 rows/block, grid 2048 (target 4-5 blocks/CU = 16-20 waves/CU TLP).
// 4 waves; wave w owns 16 code-tiles ct = w*16..w*16+15 (16 codes each).
// B single-buffered in regs (low VGPR); latency hidden by TLP.
// Confident rows get the residual update fused here; fallback rows deferred.
__global__ __launch_bounds__(256, 4) void k_argmin(
    float* __restrict__ res, ushort* __restrict__ res_hl,
    const ushort* __restrict__ w_hl, const float* __restrict__ W,
    const float* __restrict__ wsq,
    int* __restrict__ idxw, float* __restrict__ idxf,
    int* __restrict__ count, int* __restrict__ fb_count,
    int* __restrict__ fb_list, int stage)
{
  __shared__ float Lm1[4][16], Lm2[4][16];
  __shared__ int   Li1[4][16];
  __shared__ int   sidx[16];
  __shared__ int   sfb[16];

  const int t = threadIdx.x;
  const int l = t & 63;
  const int w = t >> 6;            // 0..3
  const int l15 = l & 15, kg = l >> 4;
  const int row0 = blockIdx.x * 16;
  const float* wsqs = wsq + stage * NC;
  const ushort* wb = w_hl + (size_t)stage * NC * 256;

  // A fragments (all waves share the block's single 16-row tile)
  const size_t ab = (size_t)blockIdx.x * 8;
  bf16x8 ah[4], al[4];
  #pragma unroll
  for (int ks = 0; ks < 4; ++ks) {
    ah[ks] = *reinterpret_cast<const bf16x8*>(res_hl + ((ab + ks * 2) * 64 + l) * 8);
    al[ks] = *reinterpret_cast<const bf16x8*>(res_hl + ((ab + ks * 2 + 1) * 64 + l) * 8);
  }

  float m1[4], m2[4];
  int i1[4];
  #pragma unroll
  for (int rg = 0; rg < 4; ++rg) { m1[rg] = 3.4e38f; m2[rg] = 3.4e38f; i1[rg] = 0; }

  #pragma unroll 2
  for (int k = 0; k < 16; ++k) {
    int ct = w * 16 + k;
    size_t bb = (size_t)ct * 8;
    bf16x8 bh[4], bl[4];
    #pragma unroll
    for (int ks = 0; ks < 4; ++ks) {
      bh[ks] = *reinterpret_cast<const bf16x8*>(wb + ((bb + ks * 2) * 64 + l) * 8);
      bl[ks] = *reinterpret_cast<const bf16x8*>(wb + ((bb + ks * 2 + 1) * 64 + l) * 8);
    }
    f32x4 accP = {0.f, 0.f, 0.f, 0.f};
    f32x4 accQ = {0.f, 0.f, 0.f, 0.f};
    #pragma unroll
    for (int ks = 0; ks < 4; ++ks) {
      accP = __builtin_amdgcn_mfma_f32_16x16x32_bf16(ah[ks], bh[ks], accP, 0, 0, 0);
      accQ = __builtin_amdgcn_mfma_f32_16x16x32_bf16(al[ks], bh[ks], accQ, 0, 0, 0);
      accQ = __builtin_amdgcn_mfma_f32_16x16x32_bf16(ah[ks], bl[ks], accQ, 0, 0, 0);
    }
    int code = ct * 16 + l15;
    float sq = wsqs[code];
    #pragma unroll
    for (int rg = 0; rg < 4; ++rg) {
      float s = fmaf(-2.f, accP[rg] + accQ[rg], sq);
      if (s < m1[rg]) { m2[rg] = m1[rg]; m1[rg] = s; i1[rg] = code; }
      else if (s < m2[rg]) m2[rg] = s;
    }
  }

  // butterfly over the 16 code-classes (lane bits 0..3)
  #pragma unroll
  for (int mk = 1; mk <= 8; mk <<= 1) {
    #pragma unroll
    for (int rg = 0; rg < 4; ++rg) {
      float om1 = __shfl_xor(m1[rg], mk);
      int   oi  = __shfl_xor(i1[rg], mk);
      float om2 = __shfl_xor(m2[rg], mk);
      bool bwin = (om1 < m1[rg]) || (om1 == m1[rg] && oi < i1[rg]);
      float lose = bwin ? m1[rg] : om1;
      m2[rg] = fminf(fminf(m2[rg], om2), lose);
      if (bwin) { m1[rg] = om1; i1[rg] = oi; }
    }
  }
  if (l15 == 0) {
    #pragma unroll
    for (int rg = 0; rg < 4; ++rg) {
      Lm1[w][kg * 4 + rg] = m1[rg];
      Lm2[w][kg * 4 + rg] = m2[rg];
      Li1[w][kg * 4 + rg] = i1[rg];
    }
  }
  __syncthreads();

  if (t < 16) {
    float gm1 = Lm1[0][t], gm2 = Lm2[0][t];
    int gi = Li1[0][t];
    #pragma unroll
    for (int q = 1; q < 4; ++q) {
      float b1 = Lm1[q][t], b2 = Lm2[q][t];
      int bi = Li1[q][t];
      bool bwin = (b1 < gm1) || (b1 == gm1 && bi < gi);
      float lose = bwin ? gm1 : b1;
      gm2 = fminf(fminf(gm2, b2), lose);
      if (bwin) { gm1 = b1; gi = bi; }
    }
    int row = row0 + t;
    if (gm2 - gm1 > TAU) {
      idxw[row] = gi;
      idxf[row] = (float)gi;
      atomicAdd(&count[gi], 1);
      sidx[t] = gi; sfb[t] = 0;
    } else {
      int p = atomicAdd(fb_count, 1);
      fb_list[p] = row;
      sidx[t] = 0; sfb[t] = 1;
    }
  }
  __syncthreads();

  // fused residual update for confident rows (fallback rows deferred)
  {
    int rloc = t >> 4, g = t & 15;
    if (!sfb[rloc]) {
      int row = row0 + rloc;
      int id = sidx[rloc];
      const float4* rp = reinterpret_cast<const float4*>(res + (size_t)row * DD + g * 8);
      const float4* qp = reinterpret_cast<const float4*>(W + ((size_t)stage * NC + id) * DD + g * 8);
      float4 r0 = rp[0], r1 = rp[1];
      float4 q0 = qp[0], q1 = qp[1];
      float4 o0, o1;
      o0.x = r0.x - q0.x; o0.y = r0.y - q0.y; o0.z = r0.z - q0.z; o0.w = r0.w - q0.w;
      o1.x = r1.x - q1.x; o1.y = r1.y - q1.y; o1.z = r1.z - q1.z; o1.w = r1.w - q1.w;
      float4* wp2 = reinterpret_cast<float4*>(res + (size_t)row * DD + g * 8);
      wp2[0] = o0; wp2[1] = o1;
      ushort4 h0, h1, l0, l1;
      h0.x = f2bf(o0.x); l0.x = f2bf(o0.x - bf2f(h0.x));
      h0.y = f2bf(o0.y); l0.y = f2bf(o0.y - bf2f(h0.y));
      h0.z = f2bf(o0.z); l0.z = f2bf(o0.z - bf2f(h0.z));
      h0.w = f2bf(o0.w); l0.w = f2bf(o0.w - bf2f(h0.w));
      h1.x = f2bf(o1.x); l1.x = f2bf(o1.x - bf2f(h1.x));
      h1.y = f2bf(o1.y); l1.y = f2bf(o1.y - bf2f(h1.y));
      h1.z = f2bf(o1.z); l1.z = f2bf(o1.z - bf2f(h1.z));
      h1.w = f2bf(o1.w); l1.w = f2bf(o1.w - bf2f(h1.w));
      int ks = g >> 2, kgg = g & 3;
      size_t gb = ((size_t)(row >> 4) * 8 + ks * 2) * 64 + kgg * 16 + (row & 15);
      ushort* ph = res_hl + gb * 8;
      *reinterpret_cast<ushort4*>(ph) = h0;
      *reinterpret_cast<ushort4*>(ph + 4) = h1;
      ushort* pl = ph + 64 * 8;
      *reinterpret_cast<ushort4*>(pl) = l0;
      *reinterpret_cast<ushort4*>(pl + 4) = l1;
    }
  }
}

// ---------------------------------------------------------------- exact fp32 fallback + fused update
__global__ __launch_bounds__(256) void k_fallback(
    float* __restrict__ res, ushort* __restrict__ res_hl,
    const float* __restrict__ W, const float* __restrict__ wsq,
    const int* __restrict__ fb_count, const int* __restrict__ fb_list,
    int* __restrict__ idxw, float* __restrict__ idxf,
    int* __restrict__ count, int stage)
{
  __shared__ float rr[128];
  __shared__ float sv[256];
  __shared__ int   si[256];
  int n = *fb_count;
  int t = threadIdx.x;
  for (int b = blockIdx.x; b < n; b += gridDim.x) {
    int row = fb_list[b];
    __syncthreads();
    if (t < 128) rr[t] = res[(size_t)row * DD + t];
    __syncthreads();
    float bm = 3.4e38f; int bi = 0;
    #pragma unroll
    for (int j = 0; j < 4; ++j) {
      int c = t + j * 256;
      const float4* wp = reinterpret_cast<const float4*>(W + ((size_t)stage * NC + c) * DD);
      float dot = 0.f;
      #pragma unroll 8
      for (int k = 0; k < 32; ++k) {
        float4 wv = wp[k];
        dot = fmaf(rr[4 * k + 0], wv.x, dot);
        dot = fmaf(rr[4 * k + 1], wv.y, dot);
        dot = fmaf(rr[4 * k + 2], wv.z, dot);
        dot = fmaf(rr[4 * k + 3], wv.w, dot);
      }
      float s = fmaf(-2.f, dot, wsq[stage * NC + c]);
      if (s < bm || (s == bm && c < bi)) { bm = s; bi = c; }
    }
    sv[t] = bm; si[t] = bi;
    __syncthreads();
    for (int sft = 128; sft > 0; sft >>= 1) {
      if (t < sft) {
        float ov = sv[t + sft]; int oi = si[t + sft];
        if (ov < sv[t] || (ov == sv[t] && oi < si[t])) { sv[t] = ov; si[t] = oi; }
      }
      __syncthreads();
    }
    int win = si[0];
    if (t == 0) {
      idxw[row] = win;
      idxf[row] = (float)win;
      atomicAdd(&count[win], 1);
    }
    // fused update for this row
    if (t < 128) {
      float o = rr[t] - W[((size_t)stage * NC + win) * DD + t];
      res[(size_t)row * DD + t] = o;
      ushort hi = f2bf(o);
      ushort lo = f2bf(o - bf2f(hi));
      size_t g0 = ((size_t)(row >> 4) * 8 + (t >> 5) * 2) * 64 + ((t >> 3) & 3) * 16 + (row & 15);
      res_hl[g0 * 8 + (t & 7)] = hi;
      res_hl[(g0 + 64) * 8 + (t & 7)] = lo;
    }
  }
}

// ---------------------------------------------------------------- prefix scan + reset for next stage
__global__ __launch_bounds__(1024) void k_scan(
    int* __restrict__ count, int* __restrict__ offs, int* __restrict__ pos)
{
  __shared__ int sc[1024];
  int t = threadIdx.x;
  sc[t] = count[t];
  __syncthreads();
  for (int off = 1; off < 1024; off <<= 1) {
    int v = (t >= off) ? sc[t - off] : 0;
    __syncthreads();
    sc[t] += v;
    __syncthreads();
  }
  offs[t + 1] = sc[t];
  if (t == 0) { offs[0] = 0; count[1024] = 0; }   // count[1024] == fb_count
  pos[t] = 0;
  count[t] = 0;
}

// ---------------------------------------------------------------- CSR scatter
__global__ __launch_bounds__(256) void k_scatter(
    const int* __restrict__ idxw, const int* __restrict__ offs,
    int* __restrict__ pos, int* __restrict__ rows_sorted)
{
  int r = blockIdx.x * 256 + threadIdx.x;
  int c = idxw[r];
  int slot = offs[c] + atomicAdd(&pos[c], 1);
  rows_sorted[slot] = r;
}

// ---------------------------------------------------------------- threefry2x32 (JAX-exact)
__device__ __forceinline__ unsigned rotl32(unsigned v, int r) { return (v << r) | (v >> (32 - r)); }

__device__ void threefry2x32(unsigned ks0, unsigned ks1, unsigned x0, unsigned x1,
                             unsigned& o0, unsigned& o1)
{
  unsigned ks2 = ks0 ^ ks1 ^ 0x1BD11BDAu;
  x0 += ks0; x1 += ks1;
  x0 += x1; x1 = rotl32(x1, 13); x1 ^= x0;
  x0 += x1; x1 = rotl32(x1, 15); x1 ^= x0;
  x0 += x1; x1 = rotl32(x1, 26); x1 ^= x0;
  x0 += x1; x1 = rotl32(x1, 6);  x1 ^= x0;
  x0 += ks1; x1 += ks2 + 1u;
  x0 += x1; x1 = rotl32(x1, 17); x1 ^= x0;
  x0 += x1; x1 = rotl32(x1, 29); x1 ^= x0;
  x0 += x1; x1 = rotl32(x1, 16); x1 ^= x0;
  x0 += x1; x1 = rotl32(x1, 24); x1 ^= x0;
  x0 += ks2; x1 += ks0 + 2u;
  x0 += x1; x1 = rotl32(x1, 13); x1 ^= x0;
  x0 += x1; x1 = rotl32(x1, 15); x1 ^= x0;
  x0 += x1; x1 = rotl32(x1, 26); x1 ^= x0;
  x0 += x1; x1 = rotl32(x1, 6);  x1 ^= x0;
  x0 += ks0; x1 += ks1 + 3u;
  x0 += x1; x1 = rotl32(x1, 17); x1 ^= x0;
  x0 += x1; x1 = rotl32(x1, 29); x1 ^= x0;
  x0 += x1; x1 = rotl32(x1, 16); x1 ^= x0;
  x0 += x1; x1 = rotl32(x1, 24); x1 ^= x0;
  x0 += ks1; x1 += ks2 + 4u;
  x0 += x1; x1 = rotl32(x1, 13); x1 ^= x0;
  x0 += x1; x1 = rotl32(x1, 15); x1 ^= x0;
  x0 += x1; x1 = rotl32(x1, 26); x1 ^= x0;
  x0 += x1; x1 = rotl32(x1, 6);  x1 ^= x0;
  x0 += ks2; x1 += ks0 + 5u;
  o0 = x0; o1 = x1;
}

// ---------------------------------------------------------------- EMA / dead codes
// Reads POST-update residual; reconstructs pre-update sums:
//   sum_pre = sum_post + cnt * W[c]   (all members subtracted the same W[c])
//   pre[rid] = post[rid] + W[idx[rid]]
__global__ __launch_bounds__(1024) void k_finalize(
    const float* __restrict__ Ni_in, const float* __restrict__ mi_in,
    const int* __restrict__ offs, const int* __restrict__ rows_sorted,
    const float* __restrict__ res, const float* __restrict__ W,
    const int* __restrict__ idxw,
    float* __restrict__ outNi, float* __restrict__ outmi, float* __restrict__ outW,
    int stage)
{
  __shared__ float red[8][128];
  const float ONEMG = (float)(1.0 - 0.99);
  int c = blockIdx.x;
  int t = threadIdx.x;
  int d = t & 127;
  int jw = t >> 7;             // 0..7
  int base = offs[c];
  int cnt = offs[c + 1] - base;
  const int* rs = rows_sorted + base;

  float sum = 0.f;
  int j = jw;
  for (; j + 24 < cnt; j += 32) {
    int r0 = rs[j];
    int r1 = rs[j + 8];
    int r2 = rs[j + 16];
    int r3 = rs[j + 24];
    float v0 = res[(size_t)r0 * DD + d];
    float v1 = res[(size_t)r1 * DD + d];
    float v2 = res[(size_t)r2 * DD + d];
    float v3 = res[(size_t)r3 * DD + d];
    sum += v0 + v1 + v2 + v3;
  }
  for (; j < cnt; j += 8)
    sum += res[(size_t)rs[j] * DD + d];

  red[jw][d] = sum;
  __syncthreads();

  if (jw == 0) {
    float s8 = red[0][d] + red[1][d] + red[2][d] + red[3][d]
             + red[4][d] + red[5][d] + red[6][d] + red[7][d];
    float wc = W[((size_t)stage * NC + c) * DD + d];
    float sum_pre = fmaf((float)cnt, wc, s8);
    float ni = Ni_in[stage * NC + c] * GAMMA_F + (float)cnt * ONEMG;
    float mm = mi_in[((size_t)stage * NC + c) * DD + d] * GAMMA_F + sum_pre * ONEMG;
    float w = mm / fmaxf(ni, 1e-8f);
    if (ni < 2.0f) {
      unsigned K0, K1, a0, a1, b0, b1, o0, o1;
      threefry2x32(0u, 42u, 0u, (unsigned)stage, K0, K1);
      threefry2x32(K0, K1, 0u, 2u, a0, a1);
      threefry2x32(K0, K1, 1u, 3u, b0, b1);
      unsigned bits;
      if (c < 512) { threefry2x32(a1, b1, (unsigned)c, (unsigned)(c + 512), o0, o1); bits = o0; }
      else         { threefry2x32(a1, b1, (unsigned)(c - 512), (unsigned)c, o0, o1); bits = o1; }
      int rid = (int)(bits & 32767u);
      int idr = idxw[rid];
      w = res[(size_t)rid * DD + d] + W[((size_t)stage * NC + idr) * DD + d];
    }
    if (d == 0) outNi[stage * NC + c] = ni;
    size_t o = ((size_t)stage * NC + c) * DD + d;
    outmi[o] = mm;
    outW[o] = w;
  }
}

// ---------------------------------------------------------------- logits + loss partials
__global__ __launch_bounds__(256) void k_final(
    const float* __restrict__ data, const float* __restrict__ res,
    float* __restrict__ logits, float* __restrict__ partials)
{
  __shared__ float tile[32][33];
  __shared__ float wsum[4];
  int b = blockIdx.z, s0 = blockIdx.x << 5, d0 = blockIdx.y << 5;
  int tx = threadIdx.x, ty = threadIdx.y;
  #pragma unroll
  for (int r = 0; r < 32; r += 8)
    tile[ty + r][tx] = res[((size_t)b * SS + s0 + ty + r) * DD + d0 + tx];
  __syncthreads();
  float l = 0.f;
  #pragma unroll
  for (int r = 0; r < 32; r += 8) {
    int dv = d0 + ty + r, s = s0 + tx;
    size_t o = ((size_t)b * DD + dv) * SS + s;
    float rv = tile[tx][ty + r];
    logits[o] = data[o] - rv;
    l = fmaf(rv, rv, l);
  }
  #pragma unroll
  for (int m = 1; m < 64; m <<= 1) l += __shfl_xor(l, m);
  int lin = ty * 32 + tx;
  if ((lin & 63) == 0) wsum[lin >> 6] = l;
  __syncthreads();
  if (lin == 0) {
    int bl = (blockIdx.z * gridDim.y + blockIdx.y) * gridDim.x + blockIdx.x;
    partials[bl] = wsum[0] + wsum[1] + wsum[2] + wsum[3];
  }
}

__global__ __launch_bounds__(1024) void k_loss_reduce(
    const float* __restrict__ partials, float* __restrict__ loss)
{
  __shared__ float ws[16];
  int t = threadIdx.x;
  float s = partials[t] + partials[t + 1024] + partials[t + 2048] + partials[t + 3072];
  #pragma unroll
  for (int m = 1; m < 64; m <<= 1) s += __shfl_xor(s, m);
  if ((t & 63) == 0) ws[t >> 6] = s;
  __syncthreads();
  if (t < 16) {
    float v = ws[t];
    #pragma unroll
    for (int m = 1; m < 16; m <<= 1) v += __shfl_xor(v, m);
    if (t == 0) loss[0] = v * (1.0f / 4194304.0f);
  }
}

// ---------------------------------------------------------------- launch
extern "C" void kernel_launch(void* const* d_in, const int* in_sizes, int n_in,
                              void* d_out, int out_size, void* d_ws, size_t ws_size,
                              hipStream_t stream)
{
  (void)in_sizes; (void)n_in; (void)out_size; (void)ws_size;
  const float* data = (const float*)d_in[0];
  const float* W    = (const float*)d_in[1];
  const float* Ni   = (const float*)d_in[2];
  const float* mi   = (const float*)d_in[3];

  float* out        = (float*)d_out;
  float* out_logits = out;
  float* out_loss   = out + (size_t)BB * DD * SS;
  float* out_idx    = out_loss + 1;
  float* out_Ni     = out_idx + (size_t)NQ * RR;
  float* out_mi     = out_Ni + (size_t)NQ * NC;
  float* out_W      = out_mi + (size_t)NQ * NC * DD;

  char* wp = (char*)d_ws;
  float*  resA        = (float*)wp;   wp += (size_t)RR * DD * 4;       // 16.78 MB
  ushort* res_hl      = (ushort*)wp;  wp += (size_t)RR * DD * 4;       // 16.78 MB
  ushort* w_hl        = (ushort*)wp;  wp += (size_t)NQ * NC * DD * 4;  // 4.19 MB
  float*  wsq         = (float*)wp;   wp += (size_t)NQ * NC * 4;
  int*    idxw        = (int*)wp;     wp += (size_t)RR * 4;
  int*    fb_list     = (int*)wp;     wp += (size_t)RR * 4;
  int*    rows_sorted = (int*)wp;     wp += (size_t)RR * 4;
  int*    count       = (int*)wp;     wp += (size_t)1025 * 4;          // count[1024] + fb_count
  int*    fb_count    = count + 1024;
  int*    pos         = (int*)wp;     wp += (size_t)NC * 4;
  int*    offs        = (int*)wp;     wp += (size_t)(NC + 1) * 4;
  float*  partials    = (float*)wp;   wp += (size_t)4096 * 4;

  k_transpose_in<<<dim3(SS / 32, DD / 32, BB), dim3(32, 8), 0, stream>>>(data, resA);
  k_split<<<RR * 4 / 256, 256, 0, stream>>>(resA, res_hl);
  k_wsq<<<(NQ * NC + 255) / 256, 256, 0, stream>>>(W, wsq);
  k_split<<<NQ * NC * 4 / 256, 256, 0, stream>>>(W, w_hl);
  hipMemsetAsync(count, 0, 1025 * sizeof(int), stream);   // first stage only; k_scan resets after

  for (int i = 0; i < NQ; ++i) {
    k_argmin<<<RR / 16, 256, 0, stream>>>(resA, res_hl, w_hl, W, wsq, idxw,
                                          out_idx + (size_t)i * RR,
                                          count, fb_count, fb_list, i);
    k_fallback<<<512, 256, 0, stream>>>(resA, res_hl, W, wsq, fb_count, fb_list,
                                        idxw, out_idx + (size_t)i * RR, count, i);
    k_scan<<<1, 1024, 0, stream>>>(count, offs, pos);
    k_scatter<<<RR / 256, 256, 0, stream>>>(idxw, offs, pos, rows_sorted);
    k_finalize<<<NC, 1024, 0, stream>>>(Ni, mi, offs, rows_sorted, resA, W, idxw,
                                        out_Ni, out_mi, out_W, i);
  }

  k_final<<<dim3(SS / 32, DD / 32, BB), dim3(32, 8), 0, stream>>>(data, resA, out_logits, partials);
  k_loss_reduce<<<1, 1024, 0, stream>>>(partials, out_loss);
}